// Round 1
// baseline (911.985 us; speedup 1.0000x reference)
//
#include <hip/hip_runtime.h>

// PadeKANLayer: B=4096, IN=256, OUT=256, 8 spline terms, uniform grid of 12 pts.
// out[b,o] = sum_i silu(x[b,i])*bw[o,i]
//          + sum_i (num_spline + hw*sigmoid(50(x-hb))) / (softplus(den)+1e-4)
// den = 1 + den_spline + l2_sq[b]*l2w[o,i] + prod[b]*pw[o,i]
//
// Structure: block = 4 waves x 64 lanes. lane = b (64 b per block), block covers
// 32 o; waves split i-range 4x64, LDS-reduce at end. Weight indices are
// wave-uniform (readfirstlane on wave id) -> s_load; b-side state per lane.

#define IN_F 256
#define OUT_F 256
#define B_TOTAL 4096
#define OT 32      // o per block
#define NWAVE 4    // waves per block (i-split)

__device__ __forceinline__ float fast_exp2(float a) { return __builtin_amdgcn_exp2f(a); }
__device__ __forceinline__ float fast_log2(float a) { return __builtin_amdgcn_logf(a); }
__device__ __forceinline__ float fast_rcp(float a)  { return __builtin_amdgcn_rcpf(a); }

__global__ __launch_bounds__(256, 2)
void padekan_kernel(const float* __restrict__ x,
                    const float* __restrict__ base_w,
                    const float* __restrict__ num_w,
                    const float* __restrict__ den_w,
                    const float* __restrict__ hbias,
                    const float* __restrict__ hweight,
                    const float* __restrict__ l2w,
                    const float* __restrict__ pw,
                    const float* __restrict__ grid,
                    float* __restrict__ out)
{
    constexpr float L2E = 1.4426950408889634f;   // log2(e)
    constexpr float LN2 = 0.6931471805599453f;   // ln(2)

    __shared__ float sl2[NWAVE][64];
    __shared__ float spr[NWAVE][64];
    __shared__ float red[NWAVE][64][OT + 1];     // +1 pad: kill 32-bank conflicts

    const int lane = threadIdx.x & 63;
    const int wv = __builtin_amdgcn_readfirstlane((int)(threadIdx.x >> 6)); // wave-uniform
    const int bt = blockIdx.x >> 3;       // 64 b-tiles
    const int ot = blockIdx.x & 7;        // 8 o-tiles
    const int b_base = bt * 64;
    const int o_base = ot * OT;
    const int b = b_base + lane;

    // ---- grid (all rows identical; uniform address -> scalar loads) ----
    float gg[12];
    #pragma unroll
    for (int j = 0; j < 12; ++j) gg[j] = grid[j];
    // inverse denominators of Cox-de Boor recursion, exactly as reference
    float inv1[11], inv2[10], inv3[9];
    #pragma unroll
    for (int j = 0; j < 11; ++j) inv1[j] = 1.0f / (gg[j + 1] - gg[j] + 1e-8f);
    #pragma unroll
    for (int j = 0; j < 10; ++j) inv2[j] = 1.0f / (gg[j + 2] - gg[j] + 1e-8f);
    #pragma unroll
    for (int j = 0; j < 9; ++j)  inv3[j] = 1.0f / (gg[j + 3] - gg[j] + 1e-8f);

    // ---- per-row stats: l2_sq and prod over full i-range (cooperative) ----
    const float* xrow = x + (size_t)b * IN_F;
    {
        float pl2 = 0.f, ppr = 1.f;
        for (int ii = 0; ii < 64; ++ii) {
            float xv = xrow[wv * 64 + ii];
            pl2 = fmaf(xv, xv, pl2);
            ppr *= xv;
        }
        sl2[wv][lane] = pl2;
        spr[wv][lane] = ppr;
    }
    __syncthreads();
    const float l2v   = (sl2[0][lane] + sl2[1][lane]) + (sl2[2][lane] + sl2[3][lane]);
    const float prodv = (spr[0][lane] * spr[1][lane]) * (spr[2][lane] * spr[3][lane]);

    float acc[OT];
    #pragma unroll
    for (int oo = 0; oo < OT; ++oo) acc[oo] = 0.f;

    // ---- main loop over this wave's i-quarter ----
    for (int ii = 0; ii < 64; ++ii) {
        const int i = wv * 64 + ii;               // wave-uniform
        const float xv = xrow[i];

        // b-spline bases (order 3), exact replication of reference recursion
        float b0[11];
        #pragma unroll
        for (int j = 0; j < 11; ++j)
            b0[j] = (xv >= gg[j] && xv < gg[j + 1]) ? 1.0f : 0.0f;
        float b1[10];
        #pragma unroll
        for (int j = 0; j < 10; ++j)
            b1[j] = (xv - gg[j]) * inv1[j] * b0[j] + (gg[j + 2] - xv) * inv1[j + 1] * b0[j + 1];
        float b2[9];
        #pragma unroll
        for (int j = 0; j < 9; ++j)
            b2[j] = (xv - gg[j]) * inv2[j] * b1[j] + (gg[j + 3] - xv) * inv2[j + 1] * b1[j + 1];
        float sb[8];
        #pragma unroll
        for (int j = 0; j < 8; ++j)
            sb[j] = (xv - gg[j]) * inv3[j] * b2[j] + (gg[j + 4] - xv) * inv3[j + 1] * b2[j + 1];

        // silu(x) = x * sigmoid(x)
        const float silu_v = xv * fast_rcp(1.0f + fast_exp2(-L2E * xv));
        // heaviside arg base: sigmoid(50(x-hb)) = 1/(1+exp2(50*L2E*(hb-x)))
        const float c0 = -50.0f * L2E * xv;

        #pragma unroll
        for (int oo = 0; oo < OT; ++oo) {
            const int oi = (o_base + oo) * IN_F + i;          // wave-uniform -> s_load
            const float* wn = num_w + (size_t)oi * 8;
            const float* wd = den_w + (size_t)oi * 8;

            float num = 0.f;
            float den = fmaf(l2v, l2w[oi], fmaf(prodv, pw[oi], 1.0f));
            #pragma unroll
            for (int k = 0; k < 8; ++k) {
                num = fmaf(sb[k], wn[k], num);
                den = fmaf(sb[k], wd[k], den);
            }

            // q = 1 + exp(50(hb-x)); sigmoid = 1/q. Clamp arg to avoid inf*0.
            float arg = fminf(fmaf(hbias[oi], 50.0f * L2E, c0), 99.0f);
            float q = fast_exp2(arg) + 1.0f;

            // stable softplus(den) = max(den,0) + ln2*log2(1+exp2(-|den|*L2E))
            float t  = fast_exp2(-L2E * fabsf(den));
            float sp = fmaf(fast_log2(1.0f + t), LN2, fmaxf(den, 0.0f));

            // (num + hw/q) / den_safe  ==  (num*q + hw) * rcp(q*den_safe)
            float r = fast_rcp(q * (sp + 1e-4f));
            acc[oo] = fmaf(fmaf(num, q, hweight[oi]), r, acc[oo]);
            acc[oo] = fmaf(silu_v, base_w[oi], acc[oo]);      // fold base_out
        }
    }

    // ---- cross-wave reduction (i-split) + coalesced-ish store ----
    #pragma unroll
    for (int oo = 0; oo < OT; ++oo) red[wv][lane][oo] = acc[oo];
    __syncthreads();

    const int o_l  = threadIdx.x & (OT - 1);   // 0..31
    const int b_l0 = threadIdx.x >> 5;         // 0..7
    #pragma unroll
    for (int j = 0; j < 8; ++j) {
        const int b_l = b_l0 * 8 + j;
        float s = (red[0][b_l][o_l] + red[1][b_l][o_l]) +
                  (red[2][b_l][o_l] + red[3][b_l][o_l]);
        out[(size_t)(b_base + b_l) * OUT_F + o_base + o_l] = s;
    }
}

extern "C" void kernel_launch(void* const* d_in, const int* in_sizes, int n_in,
                              void* d_out, int out_size, void* d_ws, size_t ws_size,
                              hipStream_t stream) {
    const float* xp  = (const float*)d_in[0];
    const float* bw  = (const float*)d_in[1];
    const float* nw  = (const float*)d_in[2];
    const float* dw  = (const float*)d_in[3];
    const float* hb  = (const float*)d_in[4];
    const float* hw  = (const float*)d_in[5];
    const float* lw  = (const float*)d_in[6];
    const float* pwt = (const float*)d_in[7];
    const float* gr  = (const float*)d_in[8];
    float* outp = (float*)d_out;

    dim3 grid((B_TOTAL / 64) * (OUT_F / OT));   // 64 b-tiles * 8 o-tiles = 512
    dim3 block(256);
    padekan_kernel<<<grid, block, 0, stream>>>(xp, bw, nw, dw, hb, hw, lw, pwt, gr, outp);
}

// Round 2
// 780.013 us; speedup vs baseline: 1.1692x; 1.1692x over previous
//
#include <hip/hip_runtime.h>

// PadeKANLayer: B=4096, IN=256, OUT=256, 8 spline terms, uniform grid of 12 pts.
// Structure: block = 4 waves x 64 lanes. lane = b (64 b per block), block covers
// OT=8 o's; waves split i-range 4x64, LDS-reduce at end. All weight indices are
// wave-uniform -> scalar loads; pre-pass packs 21 floats/(o,i) from 7 arrays
// into one 24-float record in d_ws so the inner loop is 2 s_loads, not 7.

#define IN_F 256
#define OUT_F 256
#define B_TOTAL 4096
#define OT 8       // o per block (8 -> 2048 blocks -> ~75% occupancy)
#define NWAVE 4    // waves per block (i-split)
#define REC 24     // packed record floats per (o,i)

constexpr float L2E = 1.4426950408889634f;   // log2(e)
constexpr float LN2 = 0.6931471805599453f;   // ln(2)

__device__ __forceinline__ float fast_exp2(float a) { return __builtin_amdgcn_exp2f(a); }
__device__ __forceinline__ float fast_log2(float a) { return __builtin_amdgcn_logf(a); }
__device__ __forceinline__ float fast_rcp(float a)  { return __builtin_amdgcn_rcpf(a); }

// ---- pre-pass: interleave all per-(o,i) weights into one 96B record ----
__global__ __launch_bounds__(256)
void pack_kernel(const float* __restrict__ bw, const float* __restrict__ nw,
                 const float* __restrict__ dw, const float* __restrict__ hb,
                 const float* __restrict__ hw, const float* __restrict__ lw,
                 const float* __restrict__ pw, float* __restrict__ packed)
{
    const int oi = blockIdx.x * 256 + threadIdx.x;      // 0 .. 65535
    float* r = packed + (size_t)oi * REC;
    const float* n8 = nw + (size_t)oi * 8;
    const float* d8 = dw + (size_t)oi * 8;
    #pragma unroll
    for (int k = 0; k < 8; ++k) r[k] = n8[k];
    #pragma unroll
    for (int k = 0; k < 8; ++k) r[8 + k] = d8[k];
    r[16] = bw[oi];
    r[17] = hb[oi] * (50.0f * L2E);   // pre-scaled heaviside bias
    r[18] = hw[oi];
    r[19] = lw[oi];
    r[20] = pw[oi];
    r[21] = 0.f; r[22] = 0.f; r[23] = 0.f;
}

template <bool PACKED>
__global__ __launch_bounds__(256, 6)   // cap VGPR at 512/6=85 -> 6 blocks/CU
void padekan_kernel(const float* __restrict__ x,
                    const float* __restrict__ base_w,
                    const float* __restrict__ num_w,
                    const float* __restrict__ den_w,
                    const float* __restrict__ hbias,
                    const float* __restrict__ hweight,
                    const float* __restrict__ l2w,
                    const float* __restrict__ pw,
                    const float* __restrict__ grid,
                    const float* __restrict__ packed,
                    float* __restrict__ out)
{
    __shared__ float sl2[NWAVE][64];
    __shared__ float spr[NWAVE][64];
    __shared__ float red[NWAVE][64][OT + 1];     // +1 pad: kill bank conflicts

    const int lane = threadIdx.x & 63;
    const int wv = __builtin_amdgcn_readfirstlane((int)(threadIdx.x >> 6)); // uniform
    const int bt = blockIdx.x >> 5;        // 64 b-tiles
    const int ot = blockIdx.x & 31;        // 32 o-tiles
    const int b_base = bt * 64;
    const int o_base = ot * OT;
    const int b = b_base + lane;

    // ---- grid (uniform address -> scalar loads) ----
    float gg[12];
    #pragma unroll
    for (int j = 0; j < 12; ++j) gg[j] = grid[j];
    float inv1[11], inv2[10], inv3[9];
    #pragma unroll
    for (int j = 0; j < 11; ++j) inv1[j] = 1.0f / (gg[j + 1] - gg[j] + 1e-8f);
    #pragma unroll
    for (int j = 0; j < 10; ++j) inv2[j] = 1.0f / (gg[j + 2] - gg[j] + 1e-8f);
    #pragma unroll
    for (int j = 0; j < 9; ++j)  inv3[j] = 1.0f / (gg[j + 3] - gg[j] + 1e-8f);

    // ---- per-row stats: l2_sq and prod (cooperative across the 4 waves) ----
    const float* xrow = x + (size_t)b * IN_F;
    {
        float pl2 = 0.f, ppr = 1.f;
        for (int ii = 0; ii < 64; ++ii) {
            float xv = xrow[wv * 64 + ii];
            pl2 = fmaf(xv, xv, pl2);
            ppr *= xv;
        }
        sl2[wv][lane] = pl2;
        spr[wv][lane] = ppr;
    }
    __syncthreads();
    const float l2v   = (sl2[0][lane] + sl2[1][lane]) + (sl2[2][lane] + sl2[3][lane]);
    const float prodv = (spr[0][lane] * spr[1][lane]) * (spr[2][lane] * spr[3][lane]);

    float acc[OT];
    #pragma unroll
    for (int oo = 0; oo < OT; ++oo) acc[oo] = 0.f;

    // ---- main loop over this wave's i-quarter ----
    for (int ii = 0; ii < 64; ++ii) {
        const int i = wv * 64 + ii;               // wave-uniform
        const float xv = xrow[i];

        // b-spline bases (order 3), exact replication of reference recursion
        float b0[11];
        #pragma unroll
        for (int j = 0; j < 11; ++j)
            b0[j] = (xv >= gg[j] && xv < gg[j + 1]) ? 1.0f : 0.0f;
        float b1[10];
        #pragma unroll
        for (int j = 0; j < 10; ++j)
            b1[j] = (xv - gg[j]) * inv1[j] * b0[j] + (gg[j + 2] - xv) * inv1[j + 1] * b0[j + 1];
        float b2[9];
        #pragma unroll
        for (int j = 0; j < 9; ++j)
            b2[j] = (xv - gg[j]) * inv2[j] * b1[j] + (gg[j + 3] - xv) * inv2[j + 1] * b1[j + 1];
        float sb[8];
        #pragma unroll
        for (int j = 0; j < 8; ++j)
            sb[j] = (xv - gg[j]) * inv3[j] * b2[j] + (gg[j + 4] - xv) * inv3[j + 1] * b2[j + 1];

        const float silu_v = xv * fast_rcp(1.0f + fast_exp2(-L2E * xv));
        const float c0 = -50.0f * L2E * xv;       // sigmoid(50(x-hb)) = 1/(1+exp2(hb'-c0))

        #pragma unroll
        for (int oo = 0; oo < OT; ++oo) {
            const int oi = (o_base + oo) * IN_F + i;          // wave-uniform

            float wn[8], wd[8], w_bw, w_hb, w_hw, w_l2, w_pr;
            if constexpr (PACKED) {
                const float* rec = packed + (size_t)oi * REC;
                #pragma unroll
                for (int k = 0; k < 8; ++k) { wn[k] = rec[k]; wd[k] = rec[8 + k]; }
                w_bw = rec[16]; w_hb = rec[17]; w_hw = rec[18];
                w_l2 = rec[19]; w_pr = rec[20];
            } else {
                const float* n8 = num_w + (size_t)oi * 8;
                const float* d8 = den_w + (size_t)oi * 8;
                #pragma unroll
                for (int k = 0; k < 8; ++k) { wn[k] = n8[k]; wd[k] = d8[k]; }
                w_bw = base_w[oi]; w_hb = hbias[oi] * (50.0f * L2E); w_hw = hweight[oi];
                w_l2 = l2w[oi]; w_pr = pw[oi];
            }

            float num = 0.f;
            float den = fmaf(l2v, w_l2, fmaf(prodv, w_pr, 1.0f));
            #pragma unroll
            for (int k = 0; k < 8; ++k) {
                num = fmaf(sb[k], wn[k], num);
                den = fmaf(sb[k], wd[k], den);
            }

            // q = 1 + exp(50(hb-x)); sigmoid = 1/q. Clamp arg to avoid inf*0.
            float arg = fminf(w_hb + c0, 99.0f);
            float q = fast_exp2(arg) + 1.0f;

            // stable softplus(den) = max(den,0) + ln2*log2(1+exp2(-|den|*L2E))
            float t  = fast_exp2(-L2E * fabsf(den));
            float sp = fmaf(fast_log2(1.0f + t), LN2, fmaxf(den, 0.0f));

            // (num + hw/q) / den_safe == (num*q + hw) * rcp(q*den_safe)
            float r = fast_rcp(q * (sp + 1e-4f));
            acc[oo] = fmaf(fmaf(num, q, w_hw), r, acc[oo]);
            acc[oo] = fmaf(silu_v, w_bw, acc[oo]);            // fold base_out
        }
    }

    // ---- cross-wave reduction (i-split) + store ----
    #pragma unroll
    for (int oo = 0; oo < OT; ++oo) red[wv][lane][oo] = acc[oo];
    __syncthreads();

    #pragma unroll
    for (int rr = 0; rr < (64 * OT) / 256; ++rr) {
        const int idx = rr * 256 + threadIdx.x;
        const int b_l = idx / OT;
        const int o_l = idx % OT;
        float s = (red[0][b_l][o_l] + red[1][b_l][o_l]) +
                  (red[2][b_l][o_l] + red[3][b_l][o_l]);
        out[(size_t)(b_base + b_l) * OUT_F + o_base + o_l] = s;
    }
}

extern "C" void kernel_launch(void* const* d_in, const int* in_sizes, int n_in,
                              void* d_out, int out_size, void* d_ws, size_t ws_size,
                              hipStream_t stream) {
    const float* xp  = (const float*)d_in[0];
    const float* bw  = (const float*)d_in[1];
    const float* nw  = (const float*)d_in[2];
    const float* dw  = (const float*)d_in[3];
    const float* hb  = (const float*)d_in[4];
    const float* hw  = (const float*)d_in[5];
    const float* lw  = (const float*)d_in[6];
    const float* pwt = (const float*)d_in[7];
    const float* gr  = (const float*)d_in[8];
    float* outp = (float*)d_out;
    float* packed = (float*)d_ws;

    const size_t need = (size_t)OUT_F * IN_F * REC * sizeof(float);   // 6.3 MB
    dim3 grid((B_TOTAL / 64) * (OUT_F / OT));   // 64 * 32 = 2048 blocks
    dim3 block(256);

    if (ws_size >= need) {
        pack_kernel<<<dim3((OUT_F * IN_F) / 256), block, 0, stream>>>(
            bw, nw, dw, hb, hw, lw, pwt, packed);
        padekan_kernel<true><<<grid, block, 0, stream>>>(
            xp, bw, nw, dw, hb, hw, lw, pwt, gr, packed, outp);
    } else {
        padekan_kernel<false><<<grid, block, 0, stream>>>(
            xp, bw, nw, dw, hb, hw, lw, pwt, gr, (const float*)nullptr, outp);
    }
}

// Round 3
// 529.762 us; speedup vs baseline: 1.7215x; 1.4724x over previous
//
#include <hip/hip_runtime.h>

// PadeKANLayer: B=4096, IN=256, OUT=256, 8 spline terms, uniform grid of 12 pts.
// R3 structure: block = 4 waves x 64 lanes; lane covers 2 b's (b, b+64) -> 128 b
// per block; block covers OT=8 o's; waves split i-range 4x64; LDS-reduce.
// XCD swizzle: blockIdx&7 -> o-group of 4 tiles => per-XCD weight set 0.79 MB
// (fits 4 MiB L2). Pre-passes: pack 21 weight floats/(o,i) into 96B records
// (2 s_loads/iter) and transpose x -> xT[i][b] for coalesced vector loads.

#define IN_F 256
#define OUT_F 256
#define B_TOTAL 4096
#define OT 8       // o per block
#define NB 128     // b per block (2 per lane)
#define NWAVE 4    // waves per block (i-split)
#define REC 24     // packed record floats per (o,i)

constexpr float L2E = 1.4426950408889634f;   // log2(e)
constexpr float LN2 = 0.6931471805599453f;   // ln(2)

__device__ __forceinline__ float fast_exp2(float a) { return __builtin_amdgcn_exp2f(a); }
__device__ __forceinline__ float fast_log2(float a) { return __builtin_amdgcn_logf(a); }
__device__ __forceinline__ float fast_rcp(float a)  { return __builtin_amdgcn_rcpf(a); }

// ---- pre-pass 1: interleave all per-(o,i) weights into one 96B record ----
__global__ __launch_bounds__(256)
void pack_kernel(const float* __restrict__ bw, const float* __restrict__ nw,
                 const float* __restrict__ dw, const float* __restrict__ hb,
                 const float* __restrict__ hw, const float* __restrict__ lw,
                 const float* __restrict__ pw, float* __restrict__ packed)
{
    const int oi = blockIdx.x * 256 + threadIdx.x;      // 0 .. 65535
    float* r = packed + (size_t)oi * REC;
    const float* n8 = nw + (size_t)oi * 8;
    const float* d8 = dw + (size_t)oi * 8;
    #pragma unroll
    for (int k = 0; k < 8; ++k) r[k] = n8[k];
    #pragma unroll
    for (int k = 0; k < 8; ++k) r[8 + k] = d8[k];
    r[16] = bw[oi];
    r[17] = hb[oi] * (50.0f * L2E);   // pre-scaled heaviside bias
    r[18] = hw[oi];
    r[19] = lw[oi];
    r[20] = pw[oi];
    r[21] = 0.f; r[22] = 0.f; r[23] = 0.f;
}

// ---- pre-pass 2: transpose x[b][i] -> xT[i][b] (coalesced main-loop loads) --
__global__ __launch_bounds__(256)
void transpose_kernel(const float* __restrict__ x, float* __restrict__ xT)
{
    __shared__ float t[64][65];
    const int bt = blockIdx.x >> 2;   // 64 b-tiles
    const int it = blockIdx.x & 3;    // 4 i-tiles
    const int c  = threadIdx.x & 63;
    const int r0 = threadIdx.x >> 6;  // 0..3
    #pragma unroll
    for (int rr = 0; rr < 16; ++rr) {
        const int r = r0 * 16 + rr;   // b within tile
        t[r][c] = x[(size_t)(bt * 64 + r) * IN_F + it * 64 + c];
    }
    __syncthreads();
    #pragma unroll
    for (int rr = 0; rr < 16; ++rr) {
        const int r = r0 * 16 + rr;   // i within tile
        xT[(size_t)(it * 64 + r) * B_TOTAL + bt * 64 + c] = t[c][r];
    }
}

// MODE: 0 = plain inputs, 1 = packed weights, 2 = packed + transposed x
template <int MODE>
__global__ __launch_bounds__(256, 4)   // 4 blocks/CU, VGPR cap 128
void padekan_kernel(const float* __restrict__ x,
                    const float* __restrict__ base_w,
                    const float* __restrict__ num_w,
                    const float* __restrict__ den_w,
                    const float* __restrict__ hbias,
                    const float* __restrict__ hweight,
                    const float* __restrict__ l2w,
                    const float* __restrict__ pw,
                    const float* __restrict__ grid,
                    const float* __restrict__ packed,
                    const float* __restrict__ xT,
                    float* __restrict__ out)
{
    __shared__ float sl2[NWAVE][NB];
    __shared__ float spr[NWAVE][NB];
    __shared__ float red[NWAVE][NB][OT + 1];     // +1 pad

    const int lane = threadIdx.x & 63;
    const int wv = __builtin_amdgcn_readfirstlane((int)(threadIdx.x >> 6));
    // XCD swizzle: g = blockIdx&7 follows round-robin XCD dispatch; give each
    // XCD a fixed group of 4 o-tiles so its L2 holds only 0.79 MB of weights.
    const int g  = blockIdx.x & 7;
    const int r  = blockIdx.x >> 3;        // 0..127
    const int ot = g * 4 + (r & 3);        // 32 o-tiles
    const int bt = r >> 2;                 // 32 b-tiles
    const int b_base = bt * NB;
    const int o_base = ot * OT;
    const int b0 = b_base + lane;
    const int b1 = b0 + 64;

    // ---- grid knots (uniform -> scalar) ----
    float gg[12];
    #pragma unroll
    for (int j = 0; j < 12; ++j) gg[j] = grid[j];
    float inv1[11], inv2[10], inv3[9];
    #pragma unroll
    for (int j = 0; j < 11; ++j) inv1[j] = 1.0f / (gg[j + 1] - gg[j] + 1e-8f);
    #pragma unroll
    for (int j = 0; j < 10; ++j) inv2[j] = 1.0f / (gg[j + 2] - gg[j] + 1e-8f);
    #pragma unroll
    for (int j = 0; j < 9; ++j)  inv3[j] = 1.0f / (gg[j + 3] - gg[j] + 1e-8f);

    auto load_x = [&](int i, int b) -> float {
        if constexpr (MODE == 2) return xT[(size_t)i * B_TOTAL + b];
        else                     return x[(size_t)b * IN_F + i];
    };

    // ---- per-row stats: l2_sq and prod (cooperative across waves) ----
    {
        float pl2a = 0.f, ppra = 1.f, pl2b = 0.f, pprb = 1.f;
        for (int ii = 0; ii < 64; ++ii) {
            const int i = wv * 64 + ii;
            float xa = load_x(i, b0);
            float xb = load_x(i, b1);
            pl2a = fmaf(xa, xa, pl2a);  ppra *= xa;
            pl2b = fmaf(xb, xb, pl2b);  pprb *= xb;
        }
        sl2[wv][lane] = pl2a;  sl2[wv][64 + lane] = pl2b;
        spr[wv][lane] = ppra;  spr[wv][64 + lane] = pprb;
    }
    __syncthreads();
    const float l2v0 = (sl2[0][lane] + sl2[1][lane]) + (sl2[2][lane] + sl2[3][lane]);
    const float l2v1 = (sl2[0][64+lane] + sl2[1][64+lane]) + (sl2[2][64+lane] + sl2[3][64+lane]);
    const float pr0  = (spr[0][lane] * spr[1][lane]) * (spr[2][lane] * spr[3][lane]);
    const float pr1  = (spr[0][64+lane] * spr[1][64+lane]) * (spr[2][64+lane] * spr[3][64+lane]);

    float acc0[OT], acc1[OT];
    #pragma unroll
    for (int oo = 0; oo < OT; ++oo) { acc0[oo] = 0.f; acc1[oo] = 0.f; }

    // ---- main loop over this wave's i-quarter ----
    for (int ii = 0; ii < 64; ++ii) {
        const int i = wv * 64 + ii;               // wave-uniform
        const float xa = load_x(i, b0);
        const float xb = load_x(i, b1);

        // b-spline bases (order 3) for both b's — exact reference recursion
        float sba[8], sbb[8];
        {
            float a0[11], c0_[11];
            #pragma unroll
            for (int j = 0; j < 11; ++j) {
                a0[j]  = (xa >= gg[j] && xa < gg[j + 1]) ? 1.0f : 0.0f;
                c0_[j] = (xb >= gg[j] && xb < gg[j + 1]) ? 1.0f : 0.0f;
            }
            float a1[10], c1[10];
            #pragma unroll
            for (int j = 0; j < 10; ++j) {
                a1[j] = (xa - gg[j]) * inv1[j] * a0[j]  + (gg[j + 2] - xa) * inv1[j + 1] * a0[j + 1];
                c1[j] = (xb - gg[j]) * inv1[j] * c0_[j] + (gg[j + 2] - xb) * inv1[j + 1] * c0_[j + 1];
            }
            float a2[9], c2[9];
            #pragma unroll
            for (int j = 0; j < 9; ++j) {
                a2[j] = (xa - gg[j]) * inv2[j] * a1[j] + (gg[j + 3] - xa) * inv2[j + 1] * a1[j + 1];
                c2[j] = (xb - gg[j]) * inv2[j] * c1[j] + (gg[j + 3] - xb) * inv2[j + 1] * c1[j + 1];
            }
            #pragma unroll
            for (int j = 0; j < 8; ++j) {
                sba[j] = (xa - gg[j]) * inv3[j] * a2[j] + (gg[j + 4] - xa) * inv3[j + 1] * a2[j + 1];
                sbb[j] = (xb - gg[j]) * inv3[j] * c2[j] + (gg[j + 4] - xb) * inv3[j + 1] * c2[j + 1];
            }
        }

        const float silu0 = xa * fast_rcp(1.0f + fast_exp2(-L2E * xa));
        const float silu1 = xb * fast_rcp(1.0f + fast_exp2(-L2E * xb));
        const float ca = -50.0f * L2E * xa;
        const float cb = -50.0f * L2E * xb;

        #pragma unroll
        for (int oo = 0; oo < OT; ++oo) {
            const int oi = (o_base + oo) * IN_F + i;          // wave-uniform

            float wn[8], wd[8], w_bw, w_hb, w_hw, w_l2, w_pr;
            if constexpr (MODE >= 1) {
                const float* rec = packed + (size_t)oi * REC;
                #pragma unroll
                for (int k = 0; k < 8; ++k) { wn[k] = rec[k]; wd[k] = rec[8 + k]; }
                w_bw = rec[16]; w_hb = rec[17]; w_hw = rec[18];
                w_l2 = rec[19]; w_pr = rec[20];
            } else {
                const float* n8 = num_w + (size_t)oi * 8;
                const float* d8 = den_w + (size_t)oi * 8;
                #pragma unroll
                for (int k = 0; k < 8; ++k) { wn[k] = n8[k]; wd[k] = d8[k]; }
                w_bw = base_w[oi]; w_hb = hbias[oi] * (50.0f * L2E); w_hw = hweight[oi];
                w_l2 = l2w[oi]; w_pr = pw[oi];
            }

            float num0 = 0.f, num1 = 0.f;
            float den0 = fmaf(l2v0, w_l2, fmaf(pr0, w_pr, 1.0f));
            float den1 = fmaf(l2v1, w_l2, fmaf(pr1, w_pr, 1.0f));
            #pragma unroll
            for (int k = 0; k < 8; ++k) {
                num0 = fmaf(sba[k], wn[k], num0);
                den0 = fmaf(sba[k], wd[k], den0);
                num1 = fmaf(sbb[k], wn[k], num1);
                den1 = fmaf(sbb[k], wd[k], den1);
            }

            // q = 1 + exp(50(hb-x)); sigmoid = 1/q (arg clamped: no inf)
            float q0 = fast_exp2(fminf(w_hb + ca, 99.0f)) + 1.0f;
            float q1 = fast_exp2(fminf(w_hb + cb, 99.0f)) + 1.0f;

            // stable softplus(den) = max(den,0) + ln2*log2(1+exp2(-|den|*L2E))
            float t0 = fast_exp2(-L2E * fabsf(den0));
            float t1 = fast_exp2(-L2E * fabsf(den1));
            float sp0 = fmaf(fast_log2(1.0f + t0), LN2, fmaxf(den0, 0.0f));
            float sp1 = fmaf(fast_log2(1.0f + t1), LN2, fmaxf(den1, 0.0f));

            // (num + hw/q)/den_safe == (num*q + hw) * rcp(q*den_safe)
            float r0 = fast_rcp(q0 * (sp0 + 1e-4f));
            float r1 = fast_rcp(q1 * (sp1 + 1e-4f));
            acc0[oo] = fmaf(fmaf(num0, q0, w_hw), r0, acc0[oo]);
            acc1[oo] = fmaf(fmaf(num1, q1, w_hw), r1, acc1[oo]);
            acc0[oo] = fmaf(silu0, w_bw, acc0[oo]);
            acc1[oo] = fmaf(silu1, w_bw, acc1[oo]);
        }
    }

    // ---- cross-wave reduction (i-split) + store ----
    #pragma unroll
    for (int oo = 0; oo < OT; ++oo) {
        red[wv][lane][oo]      = acc0[oo];
        red[wv][64 + lane][oo] = acc1[oo];
    }
    __syncthreads();

    #pragma unroll
    for (int rr = 0; rr < (NB * OT) / 256; ++rr) {
        const int idx = rr * 256 + threadIdx.x;
        const int b_l = idx >> 3;            // 0..127
        const int o_l = idx & 7;
        float s = (red[0][b_l][o_l] + red[1][b_l][o_l]) +
                  (red[2][b_l][o_l] + red[3][b_l][o_l]);
        out[(size_t)(b_base + b_l) * OUT_F + o_base + o_l] = s;
    }
}

extern "C" void kernel_launch(void* const* d_in, const int* in_sizes, int n_in,
                              void* d_out, int out_size, void* d_ws, size_t ws_size,
                              hipStream_t stream) {
    const float* xp  = (const float*)d_in[0];
    const float* bw  = (const float*)d_in[1];
    const float* nw  = (const float*)d_in[2];
    const float* dw  = (const float*)d_in[3];
    const float* hb  = (const float*)d_in[4];
    const float* hw  = (const float*)d_in[5];
    const float* lw  = (const float*)d_in[6];
    const float* pwt = (const float*)d_in[7];
    const float* gr  = (const float*)d_in[8];
    float* outp = (float*)d_out;

    const size_t xT_bytes   = (size_t)B_TOTAL * IN_F * sizeof(float);        // 4 MB
    const size_t pack_bytes = (size_t)OUT_F * IN_F * REC * sizeof(float);    // 6.3 MB

    dim3 grid((B_TOTAL / NB) * (OUT_F / OT));   // 32 * 32 = 1024 blocks
    dim3 block(256);

    if (ws_size >= xT_bytes + pack_bytes) {
        float* xT     = (float*)d_ws;
        float* packed = (float*)((char*)d_ws + xT_bytes);
        transpose_kernel<<<dim3((B_TOTAL / 64) * (IN_F / 64)), block, 0, stream>>>(xp, xT);
        pack_kernel<<<dim3((OUT_F * IN_F) / 256), block, 0, stream>>>(
            bw, nw, dw, hb, hw, lw, pwt, packed);
        padekan_kernel<2><<<grid, block, 0, stream>>>(
            xp, bw, nw, dw, hb, hw, lw, pwt, gr, packed, xT, outp);
    } else if (ws_size >= pack_bytes) {
        float* packed = (float*)d_ws;
        pack_kernel<<<dim3((OUT_F * IN_F) / 256), block, 0, stream>>>(
            bw, nw, dw, hb, hw, lw, pwt, packed);
        padekan_kernel<1><<<grid, block, 0, stream>>>(
            xp, bw, nw, dw, hb, hw, lw, pwt, gr, packed, nullptr, outp);
    } else {
        padekan_kernel<0><<<grid, block, 0, stream>>>(
            xp, bw, nw, dw, hb, hw, lw, pwt, gr, nullptr, nullptr, outp);
    }
}

// Round 4
// 439.992 us; speedup vs baseline: 2.0727x; 1.2040x over previous
//
#include <hip/hip_runtime.h>

// PadeKANLayer: B=4096, IN=256, OUT=256, 8 spline terms, UNIFORM grid (h=0.4).
// R4: closed-form uniform cubic B-spline (4 nonzero weights + dense scatter)
// replaces the Cox-de Boor recursion (~160cy vs ~412cy per (b,i)); OT 8->16
// halves spline/weight amortization. Block = 4 waves x 64 lanes; lane = b
// (64 b per block); block covers 16 o; waves split i 4x64; LDS-reduce.
// XCD swizzle: blockIdx&7 -> 2 o-tiles per XCD => 0.79 MB weights in L2.
// Pre-passes: pack 21 weight floats/(o,i) into 96B records (2 s_loads/iter),
// transpose x -> xT[i][b] for coalesced loads.

#define IN_F 256
#define OUT_F 256
#define B_TOTAL 4096
#define OT 16      // o per block
#define NB 64      // b per block (1 per lane)
#define NWAVE 4    // waves per block (i-split)
#define REC 24     // packed record floats per (o,i)

constexpr float L2E = 1.4426950408889634f;   // log2(e)
constexpr float LN2 = 0.6931471805599453f;   // ln(2)

__device__ __forceinline__ float fast_exp2(float a) { return __builtin_amdgcn_exp2f(a); }
__device__ __forceinline__ float fast_log2(float a) { return __builtin_amdgcn_logf(a); }
__device__ __forceinline__ float fast_rcp(float a)  { return __builtin_amdgcn_rcpf(a); }

// ---- pre-pass 1: interleave all per-(o,i) weights into one 96B record ----
__global__ __launch_bounds__(256)
void pack_kernel(const float* __restrict__ bw, const float* __restrict__ nw,
                 const float* __restrict__ dw, const float* __restrict__ hb,
                 const float* __restrict__ hw, const float* __restrict__ lw,
                 const float* __restrict__ pw, float* __restrict__ packed)
{
    const int oi = blockIdx.x * 256 + threadIdx.x;      // 0 .. 65535
    float* r = packed + (size_t)oi * REC;
    const float* n8 = nw + (size_t)oi * 8;
    const float* d8 = dw + (size_t)oi * 8;
    #pragma unroll
    for (int k = 0; k < 8; ++k) r[k] = n8[k];
    #pragma unroll
    for (int k = 0; k < 8; ++k) r[8 + k] = d8[k];
    r[16] = bw[oi];
    r[17] = hb[oi] * (50.0f * L2E);   // pre-scaled heaviside bias
    r[18] = hw[oi];
    r[19] = lw[oi];
    r[20] = pw[oi];
    r[21] = 0.f; r[22] = 0.f; r[23] = 0.f;
}

// ---- pre-pass 2: transpose x[b][i] -> xT[i][b] (coalesced main-loop loads) --
__global__ __launch_bounds__(256)
void transpose_kernel(const float* __restrict__ x, float* __restrict__ xT)
{
    __shared__ float t[64][65];
    const int bt = blockIdx.x >> 2;   // 64 b-tiles
    const int it = blockIdx.x & 3;    // 4 i-tiles
    const int c  = threadIdx.x & 63;
    const int r0 = threadIdx.x >> 6;  // 0..3
    #pragma unroll
    for (int rr = 0; rr < 16; ++rr) {
        const int r = r0 * 16 + rr;   // b within tile
        t[r][c] = x[(size_t)(bt * 64 + r) * IN_F + it * 64 + c];
    }
    __syncthreads();
    #pragma unroll
    for (int rr = 0; rr < 16; ++rr) {
        const int r = r0 * 16 + rr;   // i within tile
        xT[(size_t)(it * 64 + r) * B_TOTAL + bt * 64 + c] = t[c][r];
    }
}

// MODE: 0 = plain inputs, 1 = packed weights, 2 = packed + transposed x
template <int MODE>
__global__ __launch_bounds__(256, 4)
void padekan_kernel(const float* __restrict__ x,
                    const float* __restrict__ base_w,
                    const float* __restrict__ num_w,
                    const float* __restrict__ den_w,
                    const float* __restrict__ hbias,
                    const float* __restrict__ hweight,
                    const float* __restrict__ l2w,
                    const float* __restrict__ pw,
                    const float* __restrict__ grid,
                    const float* __restrict__ packed,
                    const float* __restrict__ xT,
                    float* __restrict__ out)
{
    __shared__ float sl2[NWAVE][NB];
    __shared__ float spr[NWAVE][NB];
    __shared__ float red[NWAVE][NB][OT + 1];     // +1 pad: only 2-way (free)

    const int lane = threadIdx.x & 63;
    const int wv = __builtin_amdgcn_readfirstlane((int)(threadIdx.x >> 6));
    // XCD swizzle: g = blockIdx&7 tracks round-robin XCD dispatch; each XCD
    // gets 2 fixed o-tiles -> 0.79 MB weight set resident in its 4 MiB L2.
    const int g  = blockIdx.x & 7;
    const int r  = blockIdx.x >> 3;        // 0..127
    const int ot = g * 2 + (r & 1);        // 16 o-tiles
    const int bt = r >> 1;                 // 64 b-tiles
    const int b_base = bt * NB;
    const int o_base = ot * OT;
    const int b = b_base + lane;

    // ---- uniform grid params (uniform address -> scalar loads) ----
    const float g0 = grid[0];
    const float inv_h = 1.0f / (grid[1] - grid[0]);

    auto load_x = [&](int i, int bb) -> float {
        if constexpr (MODE == 2) return xT[(size_t)i * B_TOTAL + bb];
        else                     return x[(size_t)bb * IN_F + i];
    };

    // ---- per-row stats: l2_sq and prod (cooperative across waves) ----
    {
        float pl2 = 0.f, ppr = 1.f;
        for (int ii = 0; ii < 64; ++ii) {
            float xv = load_x(wv * 64 + ii, b);
            pl2 = fmaf(xv, xv, pl2);
            ppr *= xv;
        }
        sl2[wv][lane] = pl2;
        spr[wv][lane] = ppr;
    }
    __syncthreads();
    const float l2v   = (sl2[0][lane] + sl2[1][lane]) + (sl2[2][lane] + sl2[3][lane]);
    const float prodv = (spr[0][lane] * spr[1][lane]) * (spr[2][lane] * spr[3][lane]);

    float acc[OT];
    #pragma unroll
    for (int oo = 0; oo < OT; ++oo) acc[oo] = 0.f;

    // ---- main loop over this wave's i-quarter ----
    for (int ii = 0; ii < 64; ++ii) {
        const int i = wv * 64 + ii;               // wave-uniform
        const float xv = load_x(i, b);

        // Closed-form uniform cubic B-spline: t=(x-g0)/h in [0,11) inside the
        // knot span; s=floor(t), u=t-s. Nonzero bases j=s-3..s with the
        // standard uniform weights. Matches the reference recursion to ~1e-7
        // rel (the reference's +1e-8 denominator regularizers).
        const float t  = (xv - g0) * inv_h;
        const float sf = floorf(t);
        const float u  = t - sf;
        const float u2 = u * u;
        const float u3 = u2 * u;
        const float om = 1.0f - u;
        const float W0 = om * om * om * (1.0f / 6.0f);                           // j=s-3
        const float W1 = fmaf(3.0f, u3, fmaf(-6.0f, u2, 4.0f)) * (1.0f / 6.0f);  // j=s-2
        const float W2 = fmaf(-3.0f, u3, fmaf(3.0f, u2, fmaf(3.0f, u, 1.0f))) * (1.0f / 6.0f); // j=s-1
        const float W3 = u3 * (1.0f / 6.0f);                                     // j=s
        const int  si = (int)sf;   // t<0 -> negative -> no match -> all zero
        float sb[8];
        #pragma unroll
        for (int j = 0; j < 8; ++j) {
            float v = 0.f;
            v = (si == j + 3) ? W0 : v;
            v = (si == j + 2) ? W1 : v;
            v = (si == j + 1) ? W2 : v;
            v = (si == j    ) ? W3 : v;
            sb[j] = v;
        }

        const float silu_v = xv * fast_rcp(1.0f + fast_exp2(-L2E * xv));
        const float c0 = -50.0f * L2E * xv;    // sigmoid(50(x-hb)) = 1/(1+exp2(hb'+c0))

        #pragma unroll
        for (int oo = 0; oo < OT; ++oo) {
            const int oi = (o_base + oo) * IN_F + i;          // wave-uniform

            float wn[8], wd[8], w_bw, w_hb, w_hw, w_l2, w_pr;
            if constexpr (MODE >= 1) {
                const float* rec = packed + (size_t)oi * REC;
                #pragma unroll
                for (int k = 0; k < 8; ++k) { wn[k] = rec[k]; wd[k] = rec[8 + k]; }
                w_bw = rec[16]; w_hb = rec[17]; w_hw = rec[18];
                w_l2 = rec[19]; w_pr = rec[20];
            } else {
                const float* n8 = num_w + (size_t)oi * 8;
                const float* d8 = den_w + (size_t)oi * 8;
                #pragma unroll
                for (int k = 0; k < 8; ++k) { wn[k] = n8[k]; wd[k] = d8[k]; }
                w_bw = base_w[oi]; w_hb = hbias[oi] * (50.0f * L2E); w_hw = hweight[oi];
                w_l2 = l2w[oi]; w_pr = pw[oi];
            }

            float num = 0.f;
            float den = fmaf(l2v, w_l2, fmaf(prodv, w_pr, 1.0f));
            #pragma unroll
            for (int k = 0; k < 8; ++k) {
                num = fmaf(sb[k], wn[k], num);
                den = fmaf(sb[k], wd[k], den);
            }

            // q = 1 + exp(50(hb-x)); sigmoid = 1/q (arg clamped: no inf)
            float q = fast_exp2(fminf(w_hb + c0, 99.0f)) + 1.0f;

            // stable softplus(den) = max(den,0) + ln2*log2(1+exp2(-|den|*L2E))
            float tt = fast_exp2(-L2E * fabsf(den));
            float sp = fmaf(fast_log2(1.0f + tt), LN2, fmaxf(den, 0.0f));

            // (num + hw/q)/den_safe == (num*q + hw) * rcp(q*den_safe)
            float rr = fast_rcp(q * (sp + 1e-4f));
            acc[oo] = fmaf(silu_v, w_bw, fmaf(fmaf(num, q, w_hw), rr, acc[oo]));
        }
    }

    // ---- cross-wave reduction (i-split) + store ----
    #pragma unroll
    for (int oo = 0; oo < OT; ++oo) red[wv][lane][oo] = acc[oo];
    __syncthreads();

    #pragma unroll
    for (int rr = 0; rr < (NB * OT) / 256; ++rr) {
        const int idx = rr * 256 + threadIdx.x;
        const int b_l = idx >> 4;            // 0..63
        const int o_l = idx & 15;
        float s = (red[0][b_l][o_l] + red[1][b_l][o_l]) +
                  (red[2][b_l][o_l] + red[3][b_l][o_l]);
        out[(size_t)(b_base + b_l) * OUT_F + o_base + o_l] = s;
    }
}

extern "C" void kernel_launch(void* const* d_in, const int* in_sizes, int n_in,
                              void* d_out, int out_size, void* d_ws, size_t ws_size,
                              hipStream_t stream) {
    const float* xp  = (const float*)d_in[0];
    const float* bw  = (const float*)d_in[1];
    const float* nw  = (const float*)d_in[2];
    const float* dw  = (const float*)d_in[3];
    const float* hb  = (const float*)d_in[4];
    const float* hw  = (const float*)d_in[5];
    const float* lw  = (const float*)d_in[6];
    const float* pwt = (const float*)d_in[7];
    const float* gr  = (const float*)d_in[8];
    float* outp = (float*)d_out;

    const size_t xT_bytes   = (size_t)B_TOTAL * IN_F * sizeof(float);        // 4 MB
    const size_t pack_bytes = (size_t)OUT_F * IN_F * REC * sizeof(float);    // 6.3 MB

    dim3 grid((B_TOTAL / NB) * (OUT_F / OT));   // 64 * 16 = 1024 blocks
    dim3 block(256);

    if (ws_size >= xT_bytes + pack_bytes) {
        float* xT     = (float*)d_ws;
        float* packed = (float*)((char*)d_ws + xT_bytes);
        transpose_kernel<<<dim3((B_TOTAL / 64) * (IN_F / 64)), block, 0, stream>>>(xp, xT);
        pack_kernel<<<dim3((OUT_F * IN_F) / 256), block, 0, stream>>>(
            bw, nw, dw, hb, hw, lw, pwt, packed);
        padekan_kernel<2><<<grid, block, 0, stream>>>(
            xp, bw, nw, dw, hb, hw, lw, pwt, gr, packed, xT, outp);
    } else if (ws_size >= pack_bytes) {
        float* packed = (float*)d_ws;
        pack_kernel<<<dim3((OUT_F * IN_F) / 256), block, 0, stream>>>(
            bw, nw, dw, hb, hw, lw, pwt, packed);
        padekan_kernel<1><<<grid, block, 0, stream>>>(
            xp, bw, nw, dw, hb, hw, lw, pwt, gr, packed, nullptr, outp);
    } else {
        padekan_kernel<0><<<grid, block, 0, stream>>>(
            xp, bw, nw, dw, hb, hw, lw, pwt, gr, nullptr, nullptr, outp);
    }
}

// Round 5
// 331.033 us; speedup vs baseline: 2.7550x; 1.3292x over previous
//
#include <hip/hip_runtime.h>

// PadeKANLayer: B=4096, IN=256, OUT=256, 8 spline terms, UNIFORM grid (h=0.4).
// R5: i-split-2 grid (2048 blocks -> 8 blocks/CU, 100% occupancy target) with
// atomicAdd combine; heaviside exp folded into packed e_hb (q = fma+min, one
// less transcendental per triple); fused pre-pass. Block = 4 waves x 64 lanes;
// lane = b (64 b/block); block covers 16 o and one i-half (waves take 32 i
// each); LDS-reduce across waves, atomicAdd to out (memset-zeroed).
// XCD swizzle: blockIdx&7 -> 2 o-tiles per XCD => 0.79 MB weights in L2.

#define IN_F 256
#define OUT_F 256
#define B_TOTAL 4096
#define OT 16      // o per block
#define NB 64      // b per block (1 per lane)
#define NWAVE 4    // waves per block
#define REC 24     // packed record floats per (o,i)

constexpr float L2E = 1.4426950408889634f;   // log2(e)
constexpr float LN2 = 0.6931471805599453f;   // ln(2)

__device__ __forceinline__ float fast_exp2(float a) { return __builtin_amdgcn_exp2f(a); }
__device__ __forceinline__ float fast_log2(float a) { return __builtin_amdgcn_logf(a); }
__device__ __forceinline__ float fast_rcp(float a)  { return __builtin_amdgcn_rcpf(a); }

// ---- fused pre-pass: blocks 0..255 pack weights, 256..511 transpose x ----
__global__ __launch_bounds__(256)
void prep_kernel(const float* __restrict__ bw, const float* __restrict__ nw,
                 const float* __restrict__ dw, const float* __restrict__ hb,
                 const float* __restrict__ hw, const float* __restrict__ lw,
                 const float* __restrict__ pw, float* __restrict__ packed,
                 const float* __restrict__ x, float* __restrict__ xT)
{
    if (blockIdx.x < 256) {
        const int oi = blockIdx.x * 256 + threadIdx.x;      // 0 .. 65535
        float* r = packed + (size_t)oi * REC;
        const float* n8 = nw + (size_t)oi * 8;
        const float* d8 = dw + (size_t)oi * 8;
        #pragma unroll
        for (int k = 0; k < 8; ++k) r[k] = n8[k];
        #pragma unroll
        for (int k = 0; k < 8; ++k) r[8 + k] = d8[k];
        r[16] = bw[oi];
        r[17] = fast_exp2(hb[oi] * (50.0f * L2E));  // e_hb (finite: |arg|<~60)
        r[18] = hw[oi];
        r[19] = lw[oi];
        r[20] = pw[oi];
        r[21] = 0.f; r[22] = 0.f; r[23] = 0.f;
    } else {
        __shared__ float t[64][65];
        const int blk = blockIdx.x - 256;
        const int bt = blk >> 2;          // 64 b-tiles
        const int it = blk & 3;           // 4 i-tiles
        const int c  = threadIdx.x & 63;
        const int r0 = threadIdx.x >> 6;  // 0..3
        #pragma unroll
        for (int rr = 0; rr < 16; ++rr) {
            const int r = r0 * 16 + rr;   // b within tile
            t[r][c] = x[(size_t)(bt * 64 + r) * IN_F + it * 64 + c];
        }
        __syncthreads();
        #pragma unroll
        for (int rr = 0; rr < 16; ++rr) {
            const int r = r0 * 16 + rr;   // i within tile
            xT[(size_t)(it * 64 + r) * B_TOTAL + bt * 64 + c] = t[c][r];
        }
    }
}

// MODE: 0 = plain inputs, 1 = packed weights, 2 = packed + transposed x
template <int MODE>
__global__ __launch_bounds__(256, 8)   // 8 waves/SIMD -> VGPR cap 64
void padekan_kernel(const float* __restrict__ x,
                    const float* __restrict__ base_w,
                    const float* __restrict__ num_w,
                    const float* __restrict__ den_w,
                    const float* __restrict__ hbias,
                    const float* __restrict__ hweight,
                    const float* __restrict__ l2w,
                    const float* __restrict__ pw,
                    const float* __restrict__ grid,
                    const float* __restrict__ packed,
                    const float* __restrict__ xT,
                    float* __restrict__ out)
{
    __shared__ float sl2[NWAVE][NB];
    __shared__ float spr[NWAVE][NB];
    __shared__ float red[NWAVE][NB][OT + 1];     // 19456 B total -> 8 blocks/CU

    const int lane = threadIdx.x & 63;
    const int wv = __builtin_amdgcn_readfirstlane((int)(threadIdx.x >> 6));
    // XCD swizzle: g = blockIdx&7 tracks round-robin XCD dispatch; each XCD
    // gets 2 fixed o-tiles -> 0.79 MB weight set resident in its 4 MiB L2.
    const int g  = blockIdx.x & 7;
    const int r  = blockIdx.x >> 3;        // 0..255
    const int ot = g * 2 + (r & 1);        // 16 o-tiles
    const int ih = (r >> 1) & 1;           // i-half: 0 -> [0,128), 1 -> [128,256)
    const int bt = r >> 2;                 // 64 b-tiles
    const int b_base = bt * NB;
    const int o_base = ot * OT;
    const int b = b_base + lane;

    // ---- uniform grid params (uniform address -> scalar loads) ----
    const float g0 = grid[0];
    const float inv_h = 1.0f / (grid[1] - grid[0]);

    auto load_x = [&](int i, int bb) -> float {
        if constexpr (MODE == 2) return xT[(size_t)i * B_TOTAL + bb];
        else                     return x[(size_t)bb * IN_F + i];
    };

    // ---- per-row stats over the FULL row (cooperative across 4 waves) ----
    {
        float pl2 = 0.f, ppr = 1.f;
        for (int ii = 0; ii < 64; ++ii) {
            float xv = load_x(wv * 64 + ii, b);
            pl2 = fmaf(xv, xv, pl2);
            ppr *= xv;
        }
        sl2[wv][lane] = pl2;
        spr[wv][lane] = ppr;
    }
    __syncthreads();
    const float l2v   = (sl2[0][lane] + sl2[1][lane]) + (sl2[2][lane] + sl2[3][lane]);
    const float prodv = (spr[0][lane] * spr[1][lane]) * (spr[2][lane] * spr[3][lane]);

    float acc[OT];
    #pragma unroll
    for (int oo = 0; oo < OT; ++oo) acc[oo] = 0.f;

    // ---- main loop: this wave's 32 i's within the block's i-half ----
    const int i_base = ih * 128 + wv * 32;
    for (int ii = 0; ii < 32; ++ii) {
        const int i = i_base + ii;                // wave-uniform
        const float xv = load_x(i, b);

        // Closed-form uniform cubic B-spline: t=(x-g0)/h, s=floor(t), u=t-s.
        // Nonzero bases j=s-3..s, standard uniform cubic weights (/6).
        const float t  = (xv - g0) * inv_h;
        const float sf = floorf(t);
        const float u  = t - sf;
        const float u2 = u * u;
        const float u3 = u2 * u;
        const float om = 1.0f - u;
        const float W0 = om * om * om * (1.0f / 6.0f);                           // j=s-3
        const float W1 = fmaf(3.0f, u3, fmaf(-6.0f, u2, 4.0f)) * (1.0f / 6.0f);  // j=s-2
        const float W2 = fmaf(-3.0f, u3, fmaf(3.0f, u2, fmaf(3.0f, u, 1.0f))) * (1.0f / 6.0f); // j=s-1
        const float W3 = u3 * (1.0f / 6.0f);                                     // j=s
        const int  si = (int)sf;
        float sb[8];
        #pragma unroll
        for (int j = 0; j < 8; ++j) {
            float v = 0.f;
            v = (si == j + 3) ? W0 : v;
            v = (si == j + 2) ? W1 : v;
            v = (si == j + 1) ? W2 : v;
            v = (si == j    ) ? W3 : v;
            sb[j] = v;
        }

        const float silu_v = xv * fast_rcp(1.0f + fast_exp2(-L2E * xv));
        // e_x for heaviside: sigmoid(50(x-hb)) = 1/(1 + e_hb*e_x); clamp so
        // e_x stays finite (q capped later -> exact since q cancels in ratio).
        const float e_x = fast_exp2(fminf(-50.0f * L2E * xv, 99.0f));

        #pragma unroll
        for (int oo = 0; oo < OT; ++oo) {
            const int oi = (o_base + oo) * IN_F + i;          // wave-uniform

            float wn[8], wd[8], w_bw, w_ehb, w_hw, w_l2, w_pr;
            if constexpr (MODE >= 1) {
                const float* rec = packed + (size_t)oi * REC;
                #pragma unroll
                for (int k = 0; k < 8; ++k) { wn[k] = rec[k]; wd[k] = rec[8 + k]; }
                w_bw = rec[16]; w_ehb = rec[17]; w_hw = rec[18];
                w_l2 = rec[19]; w_pr = rec[20];
            } else {
                const float* n8 = num_w + (size_t)oi * 8;
                const float* d8 = den_w + (size_t)oi * 8;
                #pragma unroll
                for (int k = 0; k < 8; ++k) { wn[k] = n8[k]; wd[k] = d8[k]; }
                w_bw = base_w[oi]; w_ehb = fast_exp2(hbias[oi] * (50.0f * L2E));
                w_hw = hweight[oi]; w_l2 = l2w[oi]; w_pr = pw[oi];
            }

            float num = 0.f;
            float den = fmaf(l2v, w_l2, fmaf(prodv, w_pr, 1.0f));
            #pragma unroll
            for (int k = 0; k < 8; ++k) {
                num = fmaf(sb[k], wn[k], num);
                den = fmaf(sb[k], wd[k], den);
            }

            // q = 1 + e_hb*e_x (cap keeps q finite; ratio exact as q cancels)
            float q = fminf(fmaf(e_x, w_ehb, 1.0f), 1e30f);

            // stable softplus(den) = max(den,0) + ln2*log2(1+exp2(-|den|*L2E))
            float tt = fast_exp2(-L2E * fabsf(den));
            float sp = fmaf(fast_log2(1.0f + tt), LN2, fmaxf(den, 0.0f));

            // (num + hw/q)/den_safe == (num*q + hw) * rcp(q*den_safe)
            float rr = fast_rcp(q * (sp + 1e-4f));
            acc[oo] = fmaf(silu_v, w_bw, fmaf(fmaf(num, q, w_hw), rr, acc[oo]));
        }
    }

    // ---- cross-wave reduction + atomic combine of the two i-halves ----
    #pragma unroll
    for (int oo = 0; oo < OT; ++oo) red[wv][lane][oo] = acc[oo];
    __syncthreads();

    #pragma unroll
    for (int rr = 0; rr < (NB * OT) / 256; ++rr) {
        const int idx = rr * 256 + threadIdx.x;
        const int b_l = idx >> 4;            // 0..63
        const int o_l = idx & 15;
        float s = (red[0][b_l][o_l] + red[1][b_l][o_l]) +
                  (red[2][b_l][o_l] + red[3][b_l][o_l]);
        atomicAdd(&out[(size_t)(b_base + b_l) * OUT_F + o_base + o_l], s);
    }
}

extern "C" void kernel_launch(void* const* d_in, const int* in_sizes, int n_in,
                              void* d_out, int out_size, void* d_ws, size_t ws_size,
                              hipStream_t stream) {
    const float* xp  = (const float*)d_in[0];
    const float* bw  = (const float*)d_in[1];
    const float* nw  = (const float*)d_in[2];
    const float* dw  = (const float*)d_in[3];
    const float* hb  = (const float*)d_in[4];
    const float* hw  = (const float*)d_in[5];
    const float* lw  = (const float*)d_in[6];
    const float* pwt = (const float*)d_in[7];
    const float* gr  = (const float*)d_in[8];
    float* outp = (float*)d_out;

    const size_t xT_bytes   = (size_t)B_TOTAL * IN_F * sizeof(float);        // 4 MB
    const size_t pack_bytes = (size_t)OUT_F * IN_F * REC * sizeof(float);    // 6.3 MB

    dim3 grid((B_TOTAL / NB) * (OUT_F / OT) * 2);   // 64 * 16 * 2 = 2048 blocks
    dim3 block(256);

    // out is accumulated atomically by the two i-half blocks -> zero it first
    hipMemsetAsync(outp, 0, (size_t)out_size * sizeof(float), stream);

    if (ws_size >= xT_bytes + pack_bytes) {
        float* xT     = (float*)d_ws;
        float* packed = (float*)((char*)d_ws + xT_bytes);
        prep_kernel<<<dim3(512), block, 0, stream>>>(
            bw, nw, dw, hb, hw, lw, pwt, packed, xp, xT);
        padekan_kernel<2><<<grid, block, 0, stream>>>(
            xp, bw, nw, dw, hb, hw, lw, pwt, gr, packed, xT, outp);
    } else if (ws_size >= pack_bytes) {
        float* packed = (float*)d_ws;
        prep_kernel<<<dim3(256), block, 0, stream>>>(
            bw, nw, dw, hb, hw, lw, pwt, packed, xp, nullptr);
        padekan_kernel<1><<<grid, block, 0, stream>>>(
            xp, bw, nw, dw, hb, hw, lw, pwt, gr, packed, nullptr, outp);
    } else {
        padekan_kernel<0><<<grid, block, 0, stream>>>(
            xp, bw, nw, dw, hb, hw, lw, pwt, gr, nullptr, nullptr, outp);
    }
}